// Round 4
// baseline (678.947 us; speedup 1.0000x reference)
//
#include <hip/hip_runtime.h>
#include <hip/hip_bf16.h>

#define D 64
#define NUM_LAYERS 4

// ---------------- CSR build ----------------

__global__ void cnt_kernel(const int* __restrict__ dst, int* __restrict__ cnt, int E) {
    int e = blockIdx.x * blockDim.x + threadIdx.x;
    if (e < E) atomicAdd(&cnt[dst[e]], 1);
}

__global__ void dis_kernel(const int* __restrict__ cnt, float* __restrict__ dis, int N) {
    int i = blockIdx.x * blockDim.x + threadIdx.x;
    if (i < N) {
        int c = cnt[i];
        dis[i] = (c > 0) ? rsqrtf((float)c) : 0.0f;
    }
}

__global__ void scan1_kernel(const int* __restrict__ cnt, int* __restrict__ excl,
                             int* __restrict__ partials, int N) {
    __shared__ int sm[256];
    int i = blockIdx.x * 256 + threadIdx.x;
    int v = (i < N) ? cnt[i] : 0;
    sm[threadIdx.x] = v;
    __syncthreads();
    for (int ofs = 1; ofs < 256; ofs <<= 1) {
        int t = (threadIdx.x >= ofs) ? sm[threadIdx.x - ofs] : 0;
        __syncthreads();
        sm[threadIdx.x] += t;
        __syncthreads();
    }
    if (i < N) excl[i] = sm[threadIdx.x] - v;
    if (threadIdx.x == 255) partials[blockIdx.x] = sm[255];
}

__global__ void scan2_kernel(int* __restrict__ partials, int nb) {
    __shared__ int sm[1024];
    int v = (threadIdx.x < nb) ? partials[threadIdx.x] : 0;
    sm[threadIdx.x] = v;
    __syncthreads();
    for (int ofs = 1; ofs < 1024; ofs <<= 1) {
        int t = (threadIdx.x >= ofs) ? sm[threadIdx.x - ofs] : 0;
        __syncthreads();
        sm[threadIdx.x] += t;
        __syncthreads();
    }
    if (threadIdx.x < nb) partials[threadIdx.x] = sm[threadIdx.x] - v;
}

__global__ void scan3_kernel(int* __restrict__ row_start, const int* __restrict__ partials,
                             int* __restrict__ cursor, int N, int E) {
    int i = blockIdx.x * 256 + threadIdx.x;
    if (i < N) {
        int v = row_start[i] + partials[blockIdx.x];
        row_start[i] = v;
        cursor[i] = v;
    }
    if (i == 0) row_start[N] = E;
}

// counting-sort edges by dst; store src only (4B/edge)
__global__ void place_kernel(const int* __restrict__ src, const int* __restrict__ dst,
                             int* __restrict__ cursor, int* __restrict__ csr_src, int E) {
    int e = blockIdx.x * blockDim.x + threadIdx.x;
    if (e < E) {
        int d = dst[e];
        int slot = atomicAdd(&cursor[d], 1);
        csr_src[slot] = src[e];
    }
}

// ---------------- propagation ----------------

// f32 concat -> bf16x2-packed A0
__global__ void init_kernel(const float* __restrict__ users, const float* __restrict__ items,
                            unsigned* __restrict__ A, int nu_elems, int total2) {
    int i = blockIdx.x * blockDim.x + threadIdx.x;   // pair index
    if (i >= total2) return;
    int base = i * 2;
    float2 v;
    if (base < nu_elems) v = ((const float2*)users)[i];
    else                 v = ((const float2*)(items))[(base - nu_elems) >> 1];
    __hip_bfloat16 bx = __float2bfloat16(v.x);
    __hip_bfloat16 by = __float2bfloat16(v.y);
    unsigned p = (unsigned)(*reinterpret_cast<unsigned short*>(&bx))
               | ((unsigned)(*reinterpret_cast<unsigned short*>(&by)) << 16);
    A[i] = p;
}

__device__ __forceinline__ float bf_lo(unsigned u) { return __uint_as_float(u << 16); }
__device__ __forceinline__ float bf_hi(unsigned u) { return __uint_as_float(u & 0xffff0000u); }

// one wave per dst node; 32 lanes x bf16x2 cover the row; 2 edges per iteration
template <int FINAL>
__global__ void gather_kernel(const int* __restrict__ row_start,
                              const int* __restrict__ csr_src,
                              const float* __restrict__ dis,
                              const __hip_bfloat16* __restrict__ A,
                              __hip_bfloat16* __restrict__ Bb,
                              float* __restrict__ Bf,
                              int N) {
    int wave = (blockIdx.x * blockDim.x + threadIdx.x) >> 6;
    if (wave >= N) return;
    int lane = threadIdx.x & 63;
    int half = lane >> 5;      // which edge of the pair this lane serves
    int col2 = lane & 31;      // which bf16x2 of the 64-wide row
    int beg = row_start[wave];
    int end = row_start[wave + 1];
    float dw = dis[wave];
    float sx = 0.0f, sy = 0.0f;
    int j = beg;
    for (; j + 4 <= end; j += 4) {
        int e0 = j + half;
        int e1 = j + 2 + half;
        int s0 = csr_src[e0];
        int s1 = csr_src[e1];
        float w0 = dis[s0] * dw;
        float w1 = dis[s1] * dw;
        unsigned u0 = *(const unsigned*)((const char*)A + ((size_t)s0 * D + col2 * 2) * 2);
        unsigned u1 = *(const unsigned*)((const char*)A + ((size_t)s1 * D + col2 * 2) * 2);
        sx += w0 * bf_lo(u0);
        sy += w0 * bf_hi(u0);
        sx += w1 * bf_lo(u1);
        sy += w1 * bf_hi(u1);
    }
    for (; j < end; j += 2) {
        int e = j + half;
        if (e < end) {
            int s = csr_src[e];
            float w = dis[s] * dw;
            unsigned u = *(const unsigned*)((const char*)A + ((size_t)s * D + col2 * 2) * 2);
            sx += w * bf_lo(u);
            sy += w * bf_hi(u);
        }
    }
    // combine the two edge streams
    sx += __shfl_xor(sx, 32);
    sy += __shfl_xor(sy, 32);
    if (half == 0) {
        if (FINAL) {
            ((float2*)(Bf + (size_t)wave * D))[col2] = make_float2(sx, sy);
        } else {
            __hip_bfloat16 bx = __float2bfloat16(sx);
            __hip_bfloat16 by = __float2bfloat16(sy);
            unsigned p = (unsigned)(*reinterpret_cast<unsigned short*>(&bx))
                       | ((unsigned)(*reinterpret_cast<unsigned short*>(&by)) << 16);
            ((unsigned*)(Bb + (size_t)wave * D))[col2] = p;
        }
    }
}

// out = (emb0 + L1 + L2 + L3 + out) / 25
__global__ void combine_kernel(const float* __restrict__ users, const float* __restrict__ items,
                               const unsigned* __restrict__ L1, const unsigned* __restrict__ L2,
                               const unsigned* __restrict__ L3, float* __restrict__ out,
                               int nu_elems, int total2) {
    int i = blockIdx.x * blockDim.x + threadIdx.x;   // pair index
    if (i >= total2) return;
    int base = i * 2;
    float2 v;
    if (base < nu_elems) v = ((const float2*)users)[i];
    else                 v = ((const float2*)items)[(base - nu_elems) >> 1];
    unsigned a = L1[i], b = L2[i], c = L3[i];
    float2 o = ((const float2*)out)[i];
    float rx = (v.x + bf_lo(a) + bf_lo(b) + bf_lo(c) + o.x) * 0.04f;
    float ry = (v.y + bf_hi(a) + bf_hi(b) + bf_hi(c) + o.y) * 0.04f;
    ((float2*)out)[i] = make_float2(rx, ry);
}

// ---------------- launch ----------------

extern "C" void kernel_launch(void* const* d_in, const int* in_sizes, int n_in,
                              void* d_out, int out_size, void* d_ws, size_t ws_size,
                              hipStream_t stream) {
    const float* users = (const float*)d_in[0];
    const float* items = (const float*)d_in[1];
    const int*   eidx  = (const int*)d_in[2];

    const int nu = in_sizes[0] / D;    // 100000
    const int ni = in_sizes[1] / D;    // 50000
    const int N  = nu + ni;            // 150000
    const int E  = in_sizes[2] / 2;    // 2000000
    const int Nf = N * D;              // 9.6M elems

    const int* src = eidx;
    const int* dst = eidx + E;

    char* ws = (char*)d_ws;
    size_t off = 0;
    auto alloc = [&](size_t bytes) {
        char* p = ws + off;
        off += (bytes + 255) & ~(size_t)255;
        return p;
    };
    int*   cnt       = (int*)alloc((size_t)N * 4);
    float* dis       = (float*)alloc((size_t)N * 4);
    int*   row_start = (int*)alloc((size_t)(N + 1) * 4);
    int*   cursor    = (int*)alloc((size_t)N * 4);
    int*   partials  = (int*)alloc(1024 * 4);
    int*   csr_src   = (int*)alloc((size_t)E * 4);
    __hip_bfloat16* A0 = (__hip_bfloat16*)alloc((size_t)Nf * 2);
    __hip_bfloat16* L1 = (__hip_bfloat16*)alloc((size_t)Nf * 2);
    __hip_bfloat16* L2 = (__hip_bfloat16*)alloc((size_t)Nf * 2);
    __hip_bfloat16* L3 = (__hip_bfloat16*)alloc((size_t)Nf * 2);

    const int B256 = 256;
    auto blocks = [](long long n, int b) { return (int)((n + b - 1) / b); };
    const int nbN = blocks(N, B256);   // 586

    // 1. degree histogram + deg_inv_sqrt
    hipMemsetAsync(cnt, 0, (size_t)N * 4, stream);
    cnt_kernel<<<blocks(E, B256), B256, 0, stream>>>(dst, cnt, E);
    dis_kernel<<<nbN, B256, 0, stream>>>(cnt, dis, N);

    // 2. exclusive scan of cnt -> row_start, cursor
    scan1_kernel<<<nbN, B256, 0, stream>>>(cnt, row_start, partials, N);
    scan2_kernel<<<1, 1024, 0, stream>>>(partials, nbN);
    scan3_kernel<<<nbN, B256, 0, stream>>>(row_start, partials, cursor, N, E);

    // 3. place edges (counting sort by dst), src-only payload
    place_kernel<<<blocks(E, B256), B256, 0, stream>>>(src, dst, cursor, csr_src, E);

    // 4. init bf16 A0
    init_kernel<<<blocks(Nf / 2, B256), B256, 0, stream>>>(users, items, (unsigned*)A0, nu * D, Nf / 2);

    // 5. propagation: L1..L3 bf16, layer 4 -> f32 into d_out
    const int ggrid = blocks(N, B256 / 64);
    gather_kernel<0><<<ggrid, B256, 0, stream>>>(row_start, csr_src, dis, A0, L1, nullptr, N);
    gather_kernel<0><<<ggrid, B256, 0, stream>>>(row_start, csr_src, dis, L1, L2, nullptr, N);
    gather_kernel<0><<<ggrid, B256, 0, stream>>>(row_start, csr_src, dis, L2, L3, nullptr, N);
    gather_kernel<1><<<ggrid, B256, 0, stream>>>(row_start, csr_src, dis, L3, nullptr, (float*)d_out, N);

    // 6. final combine: out = (emb0 + L1 + L2 + L3 + out) / 25
    combine_kernel<<<blocks(Nf / 2, B256), B256, 0, stream>>>(users, items, (const unsigned*)L1,
                                                             (const unsigned*)L2, (const unsigned*)L3,
                                                             (float*)d_out, nu * D, Nf / 2);
}

// Round 5
// 530.514 us; speedup vs baseline: 1.2798x; 1.2798x over previous
//
#include <hip/hip_runtime.h>
#include <hip/hip_bf16.h>

#define D 64
#define NUM_LAYERS 4

// ---------------- CSR build ----------------

__global__ void cnt_kernel(const int* __restrict__ dst, int* __restrict__ cnt, int E) {
    int e = blockIdx.x * blockDim.x + threadIdx.x;
    if (e < E) atomicAdd(&cnt[dst[e]], 1);
}

__global__ void dis_kernel(const int* __restrict__ cnt, float* __restrict__ dis, int N) {
    int i = blockIdx.x * blockDim.x + threadIdx.x;
    if (i < N) {
        int c = cnt[i];
        dis[i] = (c > 0) ? rsqrtf((float)c) : 0.0f;
    }
}

__global__ void scan1_kernel(const int* __restrict__ cnt, int* __restrict__ excl,
                             int* __restrict__ partials, int N) {
    __shared__ int sm[256];
    int i = blockIdx.x * 256 + threadIdx.x;
    int v = (i < N) ? cnt[i] : 0;
    sm[threadIdx.x] = v;
    __syncthreads();
    for (int ofs = 1; ofs < 256; ofs <<= 1) {
        int t = (threadIdx.x >= ofs) ? sm[threadIdx.x - ofs] : 0;
        __syncthreads();
        sm[threadIdx.x] += t;
        __syncthreads();
    }
    if (i < N) excl[i] = sm[threadIdx.x] - v;
    if (threadIdx.x == 255) partials[blockIdx.x] = sm[255];
}

__global__ void scan2_kernel(int* __restrict__ partials, int nb) {
    __shared__ int sm[1024];
    int v = (threadIdx.x < nb) ? partials[threadIdx.x] : 0;
    sm[threadIdx.x] = v;
    __syncthreads();
    for (int ofs = 1; ofs < 1024; ofs <<= 1) {
        int t = (threadIdx.x >= ofs) ? sm[threadIdx.x - ofs] : 0;
        __syncthreads();
        sm[threadIdx.x] += t;
        __syncthreads();
    }
    if (threadIdx.x < nb) partials[threadIdx.x] = sm[threadIdx.x] - v;
}

__global__ void scan3_kernel(int* __restrict__ row_start, const int* __restrict__ partials,
                             int* __restrict__ cursor, int N, int E) {
    int i = blockIdx.x * 256 + threadIdx.x;
    if (i < N) {
        int v = row_start[i] + partials[blockIdx.x];
        row_start[i] = v;
        cursor[i] = v;
    }
    if (i == 0) row_start[N] = E;
}

// counting-sort edges by dst; pack {src, norm} (round-3 form: fastest measured)
__global__ void place_kernel(const int* __restrict__ src, const int* __restrict__ dst,
                             const float* __restrict__ dis, int* __restrict__ cursor,
                             int2* __restrict__ csr, int E) {
    int e = blockIdx.x * blockDim.x + threadIdx.x;
    if (e < E) {
        int s = src[e], d = dst[e];
        int slot = atomicAdd(&cursor[d], 1);
        int2 v;
        v.x = s;
        v.y = __float_as_int(dis[s] * dis[d]);
        csr[slot] = v;
    }
}

// ---------------- propagation ----------------

__global__ void init_kernel(const float* __restrict__ users, const float* __restrict__ items,
                            unsigned* __restrict__ A, int nu_elems, int total2) {
    int i = blockIdx.x * blockDim.x + threadIdx.x;   // bf16x2 pair index
    if (i >= total2) return;
    int base = i * 2;
    float2 v;
    if (base < nu_elems) v = ((const float2*)users)[i];
    else                 v = ((const float2*)items)[(base - nu_elems) >> 1];
    __hip_bfloat16 bx = __float2bfloat16(v.x);
    __hip_bfloat16 by = __float2bfloat16(v.y);
    unsigned p = (unsigned)(*reinterpret_cast<unsigned short*>(&bx))
               | ((unsigned)(*reinterpret_cast<unsigned short*>(&by)) << 16);
    A[i] = p;
}

__device__ __forceinline__ float bf_lo(unsigned u) { return __uint_as_float(u << 16); }
__device__ __forceinline__ float bf_hi(unsigned u) { return __uint_as_float(u & 0xffff0000u); }

// One wave per dst node. Setup: one coalesced read of the node's edge segment
// (lane i holds edge beg+i), broadcast via shfl. Inner loop: 8 edges/iter,
// 4 independent row loads per lane (lanes 0-31 = even edge, 32-63 = odd edge).
template <int FINAL>
__global__ void gather_kernel(const int* __restrict__ row_start,
                              const int2* __restrict__ csr,
                              const unsigned* __restrict__ Au,   // input layer, bf16x2
                              unsigned* __restrict__ Bu,         // output layer, bf16x2 (non-final)
                              const float* __restrict__ users, const float* __restrict__ items,
                              const unsigned* __restrict__ L1u, const unsigned* __restrict__ L2u,
                              float* __restrict__ out,
                              int N, int nu) {
    int node = (blockIdx.x * blockDim.x + threadIdx.x) >> 6;
    if (node >= N) return;
    int lane = threadIdx.x & 63;
    int half = lane >> 5;
    int col2 = lane & 31;
    int beg = row_start[node];
    int end = row_start[node + 1];
    int deg = end - beg;
    float sx = 0.0f, sy = 0.0f;

    for (int base = 0; base < deg; base += 64) {
        int chunk = min(64, deg - base);
        int   sl = 0;
        float wl = 0.0f;
        if (lane < chunk) {
            int2 e = csr[beg + base + lane];
            sl = e.x;
            wl = __int_as_float(e.y);
        }
        int k = 0;
        for (; k + 8 <= chunk; k += 8) {
            int i0 = k + half, i1 = k + 2 + half, i2 = k + 4 + half, i3 = k + 6 + half;
            int   s0 = __shfl(sl, i0), s1 = __shfl(sl, i1), s2 = __shfl(sl, i2), s3 = __shfl(sl, i3);
            float w0 = __shfl(wl, i0), w1 = __shfl(wl, i1), w2 = __shfl(wl, i2), w3 = __shfl(wl, i3);
            unsigned u0 = Au[(size_t)s0 * 32 + col2];
            unsigned u1 = Au[(size_t)s1 * 32 + col2];
            unsigned u2 = Au[(size_t)s2 * 32 + col2];
            unsigned u3 = Au[(size_t)s3 * 32 + col2];
            sx += w0 * bf_lo(u0); sy += w0 * bf_hi(u0);
            sx += w1 * bf_lo(u1); sy += w1 * bf_hi(u1);
            sx += w2 * bf_lo(u2); sy += w2 * bf_hi(u2);
            sx += w3 * bf_lo(u3); sy += w3 * bf_hi(u3);
        }
        for (; k < chunk; k += 2) {
            int i0 = k + half;                  // may hit lane==chunk (wl==0 there) — harmless
            int   s = __shfl(sl, i0);
            float w = __shfl(wl, i0);
            unsigned u = Au[(size_t)s * 32 + col2];
            sx += w * bf_lo(u); sy += w * bf_hi(u);
        }
    }

    sx += __shfl_xor(sx, 32);
    sy += __shfl_xor(sy, 32);
    if (half == 0) {
        size_t ro = (size_t)node * 32 + col2;
        if (FINAL) {
            unsigned l1 = L1u[ro], l2 = L2u[ro], l3 = Au[ro];  // Au is L3 in final call
            float2 e0;
            if (node < nu) e0 = ((const float2*)users)[ro];
            else           e0 = ((const float2*)items)[(size_t)(node - nu) * 32 + col2];
            float rx = (e0.x + bf_lo(l1) + bf_lo(l2) + bf_lo(l3) + sx) * 0.04f;
            float ry = (e0.y + bf_hi(l1) + bf_hi(l2) + bf_hi(l3) + sy) * 0.04f;
            ((float2*)out)[ro] = make_float2(rx, ry);
        } else {
            __hip_bfloat16 bx = __float2bfloat16(sx);
            __hip_bfloat16 by = __float2bfloat16(sy);
            unsigned p = (unsigned)(*reinterpret_cast<unsigned short*>(&bx))
                       | ((unsigned)(*reinterpret_cast<unsigned short*>(&by)) << 16);
            Bu[ro] = p;
        }
    }
}

// ---------------- launch ----------------

extern "C" void kernel_launch(void* const* d_in, const int* in_sizes, int n_in,
                              void* d_out, int out_size, void* d_ws, size_t ws_size,
                              hipStream_t stream) {
    const float* users = (const float*)d_in[0];
    const float* items = (const float*)d_in[1];
    const int*   eidx  = (const int*)d_in[2];

    const int nu = in_sizes[0] / D;    // 100000
    const int ni = in_sizes[1] / D;    // 50000
    const int N  = nu + ni;            // 150000
    const int E  = in_sizes[2] / 2;    // 2000000
    const int Nf = N * D;              // 9.6M elems

    const int* src = eidx;
    const int* dst = eidx + E;

    char* ws = (char*)d_ws;
    size_t off = 0;
    auto alloc = [&](size_t bytes) {
        char* p = ws + off;
        off += (bytes + 255) & ~(size_t)255;
        return p;
    };
    int*   cnt       = (int*)alloc((size_t)N * 4);
    float* dis       = (float*)alloc((size_t)N * 4);
    int*   row_start = (int*)alloc((size_t)(N + 1) * 4);
    int*   cursor    = (int*)alloc((size_t)N * 4);
    int*   partials  = (int*)alloc(1024 * 4);
    int2*  csr       = (int2*)alloc((size_t)E * 8);
    unsigned* A0 = (unsigned*)alloc((size_t)Nf * 2);
    unsigned* L1 = (unsigned*)alloc((size_t)Nf * 2);
    unsigned* L2 = (unsigned*)alloc((size_t)Nf * 2);
    unsigned* L3 = (unsigned*)alloc((size_t)Nf * 2);

    const int B256 = 256;
    auto blocks = [](long long n, int b) { return (int)((n + b - 1) / b); };
    const int nbN = blocks(N, B256);

    // 1. degree histogram + deg_inv_sqrt
    hipMemsetAsync(cnt, 0, (size_t)N * 4, stream);
    cnt_kernel<<<blocks(E, B256), B256, 0, stream>>>(dst, cnt, E);
    dis_kernel<<<nbN, B256, 0, stream>>>(cnt, dis, N);

    // 2. exclusive scan of cnt -> row_start, cursor
    scan1_kernel<<<nbN, B256, 0, stream>>>(cnt, row_start, partials, N);
    scan2_kernel<<<1, 1024, 0, stream>>>(partials, nbN);
    scan3_kernel<<<nbN, B256, 0, stream>>>(row_start, partials, cursor, N, E);

    // 3. place edges (counting sort by dst), packed {src, norm}
    place_kernel<<<blocks(E, B256), B256, 0, stream>>>(src, dst, dis, cursor, csr, E);

    // 4. init bf16 A0
    init_kernel<<<blocks(Nf / 2, B256), B256, 0, stream>>>(users, items, A0, nu * D, Nf / 2);

    // 5. propagation: L1..L3 bf16; layer 4 fused with final combine -> f32 d_out
    const int ggrid = blocks(N, B256 / 64);
    gather_kernel<0><<<ggrid, B256, 0, stream>>>(row_start, csr, A0, L1, nullptr, nullptr, nullptr, nullptr, nullptr, N, nu);
    gather_kernel<0><<<ggrid, B256, 0, stream>>>(row_start, csr, L1, L2, nullptr, nullptr, nullptr, nullptr, nullptr, N, nu);
    gather_kernel<0><<<ggrid, B256, 0, stream>>>(row_start, csr, L2, L3, nullptr, nullptr, nullptr, nullptr, nullptr, N, nu);
    gather_kernel<1><<<ggrid, B256, 0, stream>>>(row_start, csr, L3, nullptr, users, items, L1, L2, (float*)d_out, N, nu);
}

// Round 6
// 464.858 us; speedup vs baseline: 1.4605x; 1.1412x over previous
//
#include <hip/hip_runtime.h>
#include <hip/hip_bf16.h>

#define D 64
#define NUM_LAYERS 4
#define TILE 4096
#define EPT 16          // edges per thread in placeA (256 thr * 16 = TILE)
#define BKMAX 320       // max buckets (N <= 163840)

// ---------------- degree / scan ----------------

__global__ void cnt_kernel(const int* __restrict__ dst, int* __restrict__ cnt, int E) {
    int e = blockIdx.x * blockDim.x + threadIdx.x;
    if (e < E) atomicAdd(&cnt[dst[e]], 1);
}

__global__ void dis_kernel(const int* __restrict__ cnt, float* __restrict__ dis, int N) {
    int i = blockIdx.x * blockDim.x + threadIdx.x;
    if (i < N) {
        int c = cnt[i];
        dis[i] = (c > 0) ? rsqrtf((float)c) : 0.0f;
    }
}

__global__ void scan1_kernel(const int* __restrict__ cnt, int* __restrict__ excl,
                             int* __restrict__ partials, int N) {
    __shared__ int sm[256];
    int i = blockIdx.x * 256 + threadIdx.x;
    int v = (i < N) ? cnt[i] : 0;
    sm[threadIdx.x] = v;
    __syncthreads();
    for (int ofs = 1; ofs < 256; ofs <<= 1) {
        int t = (threadIdx.x >= ofs) ? sm[threadIdx.x - ofs] : 0;
        __syncthreads();
        sm[threadIdx.x] += t;
        __syncthreads();
    }
    if (i < N) excl[i] = sm[threadIdx.x] - v;
    if (threadIdx.x == 255) partials[blockIdx.x] = sm[255];
}

__global__ void scan2_kernel(int* __restrict__ partials, int nb) {
    __shared__ int sm[1024];
    int v = (threadIdx.x < nb) ? partials[threadIdx.x] : 0;
    sm[threadIdx.x] = v;
    __syncthreads();
    for (int ofs = 1; ofs < 1024; ofs <<= 1) {
        int t = (threadIdx.x >= ofs) ? sm[threadIdx.x - ofs] : 0;
        __syncthreads();
        sm[threadIdx.x] += t;
        __syncthreads();
    }
    if (threadIdx.x < nb) partials[threadIdx.x] = sm[threadIdx.x] - v;
}

__global__ void scan3_kernel(int* __restrict__ row_start, const int* __restrict__ partials,
                             int N, int E) {
    int i = blockIdx.x * 256 + threadIdx.x;
    if (i < N) row_start[i] += partials[blockIdx.x];
    if (i == 0) row_start[N] = E;
}

__global__ void gcur_init_kernel(const int* __restrict__ row_start, int* __restrict__ gcur, int nbk) {
    int b = blockIdx.x * blockDim.x + threadIdx.x;
    if (b < nbk) gcur[b] = row_start[b << 9];
}

// ---------------- place: two-phase tile-partitioned counting sort ----------------

// Pass A: tile -> bucket-sorted mid. Payload: {src | (dst&511)<<18, norm}
__global__ __launch_bounds__(256) void placeA_kernel(const int* __restrict__ src,
                                                     const int* __restrict__ dst,
                                                     const float* __restrict__ dis,
                                                     int* __restrict__ gcur,
                                                     int2* __restrict__ mid,
                                                     int E, int nbk) {
    __shared__ int hist[BKMAX];
    __shared__ int gbase[BKMAX];
    int t = threadIdx.x;
    int tile0 = blockIdx.x * TILE;
    for (int i = t; i < nbk; i += 256) hist[i] = 0;
    __syncthreads();

    int   p_[EPT];   // packed src|ldst
    float w_[EPT];
    int   b_[EPT];
    int   r_[EPT];
#pragma unroll
    for (int i = 0; i < EPT; ++i) {
        int e = tile0 + i * 256 + t;
        b_[i] = -1;
        if (e < E) {
            int s = src[e], d = dst[e];
            p_[i] = s | ((d & 511) << 18);
            w_[i] = dis[s] * dis[d];
            b_[i] = d >> 9;
            r_[i] = atomicAdd(&hist[b_[i]], 1);
        }
    }
    __syncthreads();
    for (int b = t; b < nbk; b += 256) {
        int h = hist[b];
        gbase[b] = (h > 0) ? atomicAdd(&gcur[b], h) : 0;
    }
    __syncthreads();
#pragma unroll
    for (int i = 0; i < EPT; ++i) {
        if (b_[i] >= 0) {
            int pos = gbase[b_[i]] + r_[i];
            mid[pos] = make_int2(p_[i], __float_as_int(w_[i]));
        }
    }
}

// Pass B: one block per bucket; LDS per-node cursors; exact dst-sorted csr {src, w}
__global__ __launch_bounds__(256) void placeB_kernel(const int* __restrict__ row_start,
                                                     const int2* __restrict__ mid,
                                                     int2* __restrict__ csr,
                                                     int N, int nbk) {
    __shared__ int cur[512];
    int b = blockIdx.x;
    int t = threadIdx.x;
    int node0 = b << 9;
    int nend = min(512, N - node0);
    for (int i = t; i < nend; i += 256) cur[i] = row_start[node0 + i];
    __syncthreads();
    int lo = row_start[node0];
    int hi = row_start[min(node0 + 512, N)];
    for (int e = lo + t; e < hi; e += 256) {
        int2 m = mid[e];
        int ldst = (m.x >> 18) & 511;
        int s = m.x & 0x3FFFF;
        int slot = atomicAdd(&cur[ldst], 1);
        csr[slot] = make_int2(s, m.y);
    }
}

// ---------------- propagation ----------------

__global__ void init_kernel(const float* __restrict__ users, const float* __restrict__ items,
                            unsigned* __restrict__ A, int nu_elems, int total2) {
    int i = blockIdx.x * blockDim.x + threadIdx.x;   // bf16x2 pair index
    if (i >= total2) return;
    int base = i * 2;
    float2 v;
    if (base < nu_elems) v = ((const float2*)users)[i];
    else                 v = ((const float2*)items)[(base - nu_elems) >> 1];
    __hip_bfloat16 bx = __float2bfloat16(v.x);
    __hip_bfloat16 by = __float2bfloat16(v.y);
    unsigned p = (unsigned)(*reinterpret_cast<unsigned short*>(&bx))
               | ((unsigned)(*reinterpret_cast<unsigned short*>(&by)) << 16);
    A[i] = p;
}

__device__ __forceinline__ float bf_lo(unsigned u) { return __uint_as_float(u << 16); }
__device__ __forceinline__ float bf_hi(unsigned u) { return __uint_as_float(u & 0xffff0000u); }
__device__ __forceinline__ unsigned bf_pack(float x, float y) {
    __hip_bfloat16 bx = __float2bfloat16(x);
    __hip_bfloat16 by = __float2bfloat16(y);
    return (unsigned)(*reinterpret_cast<unsigned short*>(&bx))
         | ((unsigned)(*reinterpret_cast<unsigned short*>(&by)) << 16);
}

// One wave per dst node, quarter-wave per edge: q = lane>>4 picks the edge,
// c = lane&15 picks the bf16x4 (8B) chunk of the 128B row. 8 edges per iter
// -> 2 independent dwordx2 loads per lane.
template <int FINAL>
__global__ void gather_kernel(const int* __restrict__ row_start,
                              const int2* __restrict__ csr,
                              const uint2* __restrict__ Au,   // input layer, 16 x uint2 per row
                              uint2* __restrict__ Bu,         // output layer (non-final)
                              const float* __restrict__ users, const float* __restrict__ items,
                              const uint2* __restrict__ L1u, const uint2* __restrict__ L2u,
                              float* __restrict__ out,
                              int N, int nu) {
    int node = (blockIdx.x * blockDim.x + threadIdx.x) >> 6;
    if (node >= N) return;
    int lane = threadIdx.x & 63;
    int q = lane >> 4;      // edge slot within group of 4
    int c = lane & 15;      // 8B chunk of row
    int beg = row_start[node];
    int end = row_start[node + 1];
    int deg = end - beg;
    float ax = 0.0f, ay = 0.0f, az = 0.0f, aw = 0.0f;

    for (int base = 0; base < deg; base += 64) {
        int chunk = min(64, deg - base);
        int   sl = 0;
        float wl = 0.0f;
        if (lane < chunk) {
            int2 e = csr[beg + base + lane];
            sl = e.x;
            wl = __int_as_float(e.y);
        }
        int k = 0;
        for (; k + 8 <= chunk; k += 8) {
            int i0 = k + q, i1 = k + 4 + q;
            int   s0 = __shfl(sl, i0), s1 = __shfl(sl, i1);
            float w0 = __shfl(wl, i0), w1 = __shfl(wl, i1);
            uint2 u0 = Au[(size_t)s0 * 16 + c];
            uint2 u1 = Au[(size_t)s1 * 16 + c];
            ax += w0 * bf_lo(u0.x); ay += w0 * bf_hi(u0.x);
            az += w0 * bf_lo(u0.y); aw += w0 * bf_hi(u0.y);
            ax += w1 * bf_lo(u1.x); ay += w1 * bf_hi(u1.x);
            az += w1 * bf_lo(u1.y); aw += w1 * bf_hi(u1.y);
        }
        for (; k < chunk; k += 4) {
            int i0 = k + q;                 // i0 <= 63 always; lanes >= chunk carry wl=0
            int   s = __shfl(sl, i0);
            float w = __shfl(wl, i0);
            uint2 u = Au[(size_t)s * 16 + c];
            ax += w * bf_lo(u.x); ay += w * bf_hi(u.x);
            az += w * bf_lo(u.y); aw += w * bf_hi(u.y);
        }
    }

    // reduce the 4 quarter-wave streams (lanes differing in bits 4,5)
    ax += __shfl_xor(ax, 16); ay += __shfl_xor(ay, 16);
    az += __shfl_xor(az, 16); aw += __shfl_xor(aw, 16);
    ax += __shfl_xor(ax, 32); ay += __shfl_xor(ay, 32);
    az += __shfl_xor(az, 32); aw += __shfl_xor(aw, 32);

    if (q == 0) {               // lanes 0..15 hold full sums
        size_t ro = (size_t)node * 16 + c;
        if (FINAL) {
            uint2 l1 = L1u[ro], l2 = L2u[ro], l3 = Au[ro];   // Au is L3 in final call
            float4 e0;
            if (node < nu) e0 = ((const float4*)users)[ro];
            else           e0 = ((const float4*)items)[(size_t)(node - nu) * 16 + c];
            float rx = (e0.x + bf_lo(l1.x) + bf_lo(l2.x) + bf_lo(l3.x) + ax) * 0.04f;
            float ry = (e0.y + bf_hi(l1.x) + bf_hi(l2.x) + bf_hi(l3.x) + ay) * 0.04f;
            float rz = (e0.z + bf_lo(l1.y) + bf_lo(l2.y) + bf_lo(l3.y) + az) * 0.04f;
            float rw = (e0.w + bf_hi(l1.y) + bf_hi(l2.y) + bf_hi(l3.y) + aw) * 0.04f;
            ((float4*)out)[ro] = make_float4(rx, ry, rz, rw);
        } else {
            uint2 p;
            p.x = bf_pack(ax, ay);
            p.y = bf_pack(az, aw);
            Bu[ro] = p;
        }
    }
}

// ---------------- launch ----------------

extern "C" void kernel_launch(void* const* d_in, const int* in_sizes, int n_in,
                              void* d_out, int out_size, void* d_ws, size_t ws_size,
                              hipStream_t stream) {
    const float* users = (const float*)d_in[0];
    const float* items = (const float*)d_in[1];
    const int*   eidx  = (const int*)d_in[2];

    const int nu = in_sizes[0] / D;    // 100000
    const int ni = in_sizes[1] / D;    // 50000
    const int N  = nu + ni;            // 150000
    const int E  = in_sizes[2] / 2;    // 2000000
    const int Nf = N * D;              // 9.6M elems
    const int nbk = (N + 511) >> 9;    // 293 buckets

    const int* src = eidx;
    const int* dst = eidx + E;

    char* ws = (char*)d_ws;
    size_t off = 0;
    auto alloc = [&](size_t bytes) {
        char* p = ws + off;
        off += (bytes + 255) & ~(size_t)255;
        return p;
    };
    int*   cnt       = (int*)alloc((size_t)N * 4);
    float* dis       = (float*)alloc((size_t)N * 4);
    int*   row_start = (int*)alloc((size_t)(N + 1) * 4);
    int*   partials  = (int*)alloc(1024 * 4);
    int*   gcur      = (int*)alloc(512 * 4);
    int2*  csr       = (int2*)alloc((size_t)E * 8);
    unsigned* A0 = (unsigned*)alloc((size_t)Nf * 2);
    unsigned* L1 = (unsigned*)alloc((size_t)Nf * 2);
    unsigned* L2 = (unsigned*)alloc((size_t)Nf * 2);
    unsigned* L3 = (unsigned*)alloc((size_t)Nf * 2);
    int2* mid = (int2*)L3;   // alias: mid consumed (placeB) before L3 is written (gather #3)

    const int B256 = 256;
    auto blocks = [](long long n, int b) { return (int)((n + b - 1) / b); };
    const int nbN = blocks(N, B256);

    // 1. degree histogram + deg_inv_sqrt
    hipMemsetAsync(cnt, 0, (size_t)N * 4, stream);
    cnt_kernel<<<blocks(E, B256), B256, 0, stream>>>(dst, cnt, E);
    dis_kernel<<<nbN, B256, 0, stream>>>(cnt, dis, N);

    // 2. exclusive scan of cnt -> row_start
    scan1_kernel<<<nbN, B256, 0, stream>>>(cnt, row_start, partials, N);
    scan2_kernel<<<1, 1024, 0, stream>>>(partials, nbN);
    scan3_kernel<<<nbN, B256, 0, stream>>>(row_start, partials, N, E);
    gcur_init_kernel<<<blocks(nbk, B256), B256, 0, stream>>>(row_start, gcur, nbk);

    // 3. place: tile-partition into buckets, then exact scatter within buckets
    placeA_kernel<<<blocks(E, TILE), B256, 0, stream>>>(src, dst, dis, gcur, mid, E, nbk);
    placeB_kernel<<<nbk, B256, 0, stream>>>(row_start, mid, csr, N, nbk);

    // 4. init bf16 A0
    init_kernel<<<blocks(Nf / 2, B256), B256, 0, stream>>>(users, items, A0, nu * D, Nf / 2);

    // 5. propagation: L1..L3 bf16; layer 4 fused with final combine -> f32 d_out
    const int ggrid = blocks(N, B256 / 64);
    gather_kernel<0><<<ggrid, B256, 0, stream>>>(row_start, csr, (const uint2*)A0, (uint2*)L1,
                                                 nullptr, nullptr, nullptr, nullptr, nullptr, N, nu);
    gather_kernel<0><<<ggrid, B256, 0, stream>>>(row_start, csr, (const uint2*)L1, (uint2*)L2,
                                                 nullptr, nullptr, nullptr, nullptr, nullptr, N, nu);
    gather_kernel<0><<<ggrid, B256, 0, stream>>>(row_start, csr, (const uint2*)L2, (uint2*)L3,
                                                 nullptr, nullptr, nullptr, nullptr, nullptr, N, nu);
    gather_kernel<1><<<ggrid, B256, 0, stream>>>(row_start, csr, (const uint2*)L3, nullptr,
                                                 users, items, (const uint2*)L1, (const uint2*)L2,
                                                 (float*)d_out, N, nu);
}

// Round 7
// 402.694 us; speedup vs baseline: 1.6860x; 1.1544x over previous
//
#include <hip/hip_runtime.h>
#include <hip/hip_bf16.h>

#define D 64
#define NUM_LAYERS 4
#define TILE 4096
#define EPT 16          // edges per thread in placeA (256 thr * 16 = TILE)
#define BKMAX 320       // max buckets (N <= 163840)

// ---------------- bucket histogram + scan ----------------

__global__ void bhist_kernel(const int* __restrict__ dst, int* __restrict__ bcnt, int E, int nbk) {
    __shared__ int h[BKMAX];
    for (int i = threadIdx.x; i < nbk; i += blockDim.x) h[i] = 0;
    __syncthreads();
    int stride = gridDim.x * blockDim.x;
    for (int e = blockIdx.x * blockDim.x + threadIdx.x; e < E; e += stride)
        atomicAdd(&h[dst[e] >> 9], 1);
    __syncthreads();
    for (int i = threadIdx.x; i < nbk; i += blockDim.x)
        if (h[i] > 0) atomicAdd(&bcnt[i], h[i]);
}

// single block: exclusive scan of bucket counts -> bstart, gcur
__global__ __launch_bounds__(512) void bscan_kernel(const int* __restrict__ bcnt,
                                                    int* __restrict__ bstart,
                                                    int* __restrict__ gcur, int nbk, int E) {
    __shared__ int sm[512];
    int t = threadIdx.x;
    int v = (t < nbk) ? bcnt[t] : 0;
    sm[t] = v;
    __syncthreads();
    for (int ofs = 1; ofs < 512; ofs <<= 1) {
        int x = (t >= ofs) ? sm[t - ofs] : 0;
        __syncthreads();
        sm[t] += x;
        __syncthreads();
    }
    int excl = sm[t] - v;
    if (t < nbk) { bstart[t] = excl; gcur[t] = excl; }
    if (t == 0) bstart[nbk] = E;
}

// ---------------- place: two-phase tile-partitioned counting sort ----------------

// Pass A: tile -> bucket-sorted mid. Payload: src | (dst&511)<<18  (27 bits, 4B)
__global__ __launch_bounds__(256) void placeA_kernel(const int* __restrict__ src,
                                                     const int* __restrict__ dst,
                                                     int* __restrict__ gcur,
                                                     int* __restrict__ mid,
                                                     int E, int nbk) {
    __shared__ int hist[BKMAX];
    __shared__ int gbase[BKMAX];
    int t = threadIdx.x;
    int tile0 = blockIdx.x * TILE;
    for (int i = t; i < nbk; i += 256) hist[i] = 0;
    __syncthreads();

    int p_[EPT];
    int b_[EPT];
    int r_[EPT];
#pragma unroll
    for (int i = 0; i < EPT; ++i) {
        int e = tile0 + i * 256 + t;
        b_[i] = -1;
        if (e < E) {
            int s = src[e], d = dst[e];
            p_[i] = s | ((d & 511) << 18);
            b_[i] = d >> 9;
            r_[i] = atomicAdd(&hist[b_[i]], 1);
        }
    }
    __syncthreads();
    for (int b = t; b < nbk; b += 256) {
        int h = hist[b];
        gbase[b] = (h > 0) ? atomicAdd(&gcur[b], h) : 0;
    }
    __syncthreads();
#pragma unroll
    for (int i = 0; i < EPT; ++i) {
        if (b_[i] >= 0) mid[gbase[b_[i]] + r_[i]] = p_[i];
    }
}

// Pass B1: one block per bucket; per-node degree count in LDS, LDS scan ->
// row_start + deg_inv_sqrt for this bucket's 512 nodes.
__global__ __launch_bounds__(512) void placeB1_kernel(const int* __restrict__ bstart,
                                                      const int* __restrict__ mid,
                                                      int* __restrict__ row_start,
                                                      float* __restrict__ dis,
                                                      int N, int nbk, int E) {
    __shared__ int degsm[512];
    __shared__ int sc[512];
    int b = blockIdx.x;
    int t = threadIdx.x;
    int node0 = b << 9;
    int lo = bstart[b], hi = bstart[b + 1];
    degsm[t] = 0;
    __syncthreads();
    for (int e = lo + t; e < hi; e += 512)
        atomicAdd(&degsm[(mid[e] >> 18) & 511], 1);
    __syncthreads();
    int d = degsm[t];
    sc[t] = d;
    __syncthreads();
    for (int ofs = 1; ofs < 512; ofs <<= 1) {
        int x = (t >= ofs) ? sc[t - ofs] : 0;
        __syncthreads();
        sc[t] += x;
        __syncthreads();
    }
    int excl = sc[t] - d;
    int node = node0 + t;
    if (node < N) {
        row_start[node] = lo + excl;
        dis[node] = (d > 0) ? rsqrtf((float)d) : 0.0f;
    }
    if (b == nbk - 1 && t == 0) row_start[N] = E;
}

// Pass B2: scatter within bucket; compute w = dis[src]*dis[dst] once here.
__global__ __launch_bounds__(512) void placeB2_kernel(const int* __restrict__ bstart,
                                                      const int* __restrict__ mid,
                                                      const int* __restrict__ row_start,
                                                      const float* __restrict__ dis,
                                                      int2* __restrict__ csr, int N) {
    __shared__ int cur[512];
    __shared__ float dloc[512];
    int b = blockIdx.x;
    int t = threadIdx.x;
    int node0 = b << 9;
    int node = node0 + t;
    if (node < N) { cur[t] = row_start[node]; dloc[t] = dis[node]; }
    else          { cur[t] = 0; dloc[t] = 0.0f; }
    __syncthreads();
    int lo = bstart[b], hi = bstart[b + 1];
    for (int e = lo + t; e < hi; e += 512) {
        int m = mid[e];
        int l = (m >> 18) & 511;
        int s = m & 0x3FFFF;
        float w = dis[s] * dloc[l];
        int slot = atomicAdd(&cur[l], 1);
        csr[slot] = make_int2(s, __float_as_int(w));
    }
}

// ---------------- propagation ----------------

__global__ void init_kernel(const float* __restrict__ users, const float* __restrict__ items,
                            unsigned* __restrict__ A, int nu_elems, int total2) {
    int i = blockIdx.x * blockDim.x + threadIdx.x;   // bf16x2 pair index
    if (i >= total2) return;
    int base = i * 2;
    float2 v;
    if (base < nu_elems) v = ((const float2*)users)[i];
    else                 v = ((const float2*)items)[(base - nu_elems) >> 1];
    __hip_bfloat16 bx = __float2bfloat16(v.x);
    __hip_bfloat16 by = __float2bfloat16(v.y);
    unsigned p = (unsigned)(*reinterpret_cast<unsigned short*>(&bx))
               | ((unsigned)(*reinterpret_cast<unsigned short*>(&by)) << 16);
    A[i] = p;
}

__device__ __forceinline__ float bf_lo(unsigned u) { return __uint_as_float(u << 16); }
__device__ __forceinline__ float bf_hi(unsigned u) { return __uint_as_float(u & 0xffff0000u); }
__device__ __forceinline__ unsigned bf_pack(float x, float y) {
    __hip_bfloat16 bx = __float2bfloat16(x);
    __hip_bfloat16 by = __float2bfloat16(y);
    return (unsigned)(*reinterpret_cast<unsigned short*>(&bx))
         | ((unsigned)(*reinterpret_cast<unsigned short*>(&by)) << 16);
}

// One wave per dst node, quarter-wave per edge: q = lane>>4 picks the edge,
// c = lane&15 picks the bf16x4 (8B) chunk of the 128B row. 8 edges per iter.
template <int FINAL>
__global__ void gather_kernel(const int* __restrict__ row_start,
                              const int2* __restrict__ csr,
                              const uint2* __restrict__ Au,
                              uint2* __restrict__ Bu,
                              const float* __restrict__ users, const float* __restrict__ items,
                              const uint2* __restrict__ L1u, const uint2* __restrict__ L2u,
                              float* __restrict__ out,
                              int N, int nu) {
    int node = (blockIdx.x * blockDim.x + threadIdx.x) >> 6;
    if (node >= N) return;
    int lane = threadIdx.x & 63;
    int q = lane >> 4;
    int c = lane & 15;
    int beg = row_start[node];
    int end = row_start[node + 1];
    int deg = end - beg;
    float ax = 0.0f, ay = 0.0f, az = 0.0f, aw = 0.0f;

    for (int base = 0; base < deg; base += 64) {
        int chunk = min(64, deg - base);
        int   sl = 0;
        float wl = 0.0f;
        if (lane < chunk) {
            int2 e = csr[beg + base + lane];
            sl = e.x;
            wl = __int_as_float(e.y);
        }
        int k = 0;
        for (; k + 8 <= chunk; k += 8) {
            int i0 = k + q, i1 = k + 4 + q;
            int   s0 = __shfl(sl, i0), s1 = __shfl(sl, i1);
            float w0 = __shfl(wl, i0), w1 = __shfl(wl, i1);
            uint2 u0 = Au[(size_t)s0 * 16 + c];
            uint2 u1 = Au[(size_t)s1 * 16 + c];
            ax += w0 * bf_lo(u0.x); ay += w0 * bf_hi(u0.x);
            az += w0 * bf_lo(u0.y); aw += w0 * bf_hi(u0.y);
            ax += w1 * bf_lo(u1.x); ay += w1 * bf_hi(u1.x);
            az += w1 * bf_lo(u1.y); aw += w1 * bf_hi(u1.y);
        }
        for (; k < chunk; k += 4) {
            int i0 = k + q;
            int   s = __shfl(sl, i0);
            float w = __shfl(wl, i0);
            uint2 u = Au[(size_t)s * 16 + c];
            ax += w * bf_lo(u.x); ay += w * bf_hi(u.x);
            az += w * bf_lo(u.y); aw += w * bf_hi(u.y);
        }
    }

    ax += __shfl_xor(ax, 16); ay += __shfl_xor(ay, 16);
    az += __shfl_xor(az, 16); aw += __shfl_xor(aw, 16);
    ax += __shfl_xor(ax, 32); ay += __shfl_xor(ay, 32);
    az += __shfl_xor(az, 32); aw += __shfl_xor(aw, 32);

    if (q == 0) {
        size_t ro = (size_t)node * 16 + c;
        if (FINAL) {
            uint2 l1 = L1u[ro], l2 = L2u[ro], l3 = Au[ro];
            float4 e0;
            if (node < nu) e0 = ((const float4*)users)[ro];
            else           e0 = ((const float4*)items)[(size_t)(node - nu) * 16 + c];
            float rx = (e0.x + bf_lo(l1.x) + bf_lo(l2.x) + bf_lo(l3.x) + ax) * 0.04f;
            float ry = (e0.y + bf_hi(l1.x) + bf_hi(l2.x) + bf_hi(l3.x) + ay) * 0.04f;
            float rz = (e0.z + bf_lo(l1.y) + bf_lo(l2.y) + bf_lo(l3.y) + az) * 0.04f;
            float rw = (e0.w + bf_hi(l1.y) + bf_hi(l2.y) + bf_hi(l3.y) + aw) * 0.04f;
            ((float4*)out)[ro] = make_float4(rx, ry, rz, rw);
        } else {
            uint2 p;
            p.x = bf_pack(ax, ay);
            p.y = bf_pack(az, aw);
            Bu[ro] = p;
        }
    }
}

// ---------------- launch ----------------

extern "C" void kernel_launch(void* const* d_in, const int* in_sizes, int n_in,
                              void* d_out, int out_size, void* d_ws, size_t ws_size,
                              hipStream_t stream) {
    const float* users = (const float*)d_in[0];
    const float* items = (const float*)d_in[1];
    const int*   eidx  = (const int*)d_in[2];

    const int nu = in_sizes[0] / D;    // 100000
    const int ni = in_sizes[1] / D;    // 50000
    const int N  = nu + ni;            // 150000
    const int E  = in_sizes[2] / 2;    // 2000000
    const int Nf = N * D;              // 9.6M elems
    const int nbk = (N + 511) >> 9;    // 293 buckets

    const int* src = eidx;
    const int* dst = eidx + E;

    char* ws = (char*)d_ws;
    size_t off = 0;
    auto alloc = [&](size_t bytes) {
        char* p = ws + off;
        off += (bytes + 255) & ~(size_t)255;
        return p;
    };
    float* dis       = (float*)alloc((size_t)N * 4);
    int*   row_start = (int*)alloc((size_t)(N + 1) * 4);
    int*   bcnt      = (int*)alloc(BKMAX * 4);
    int*   bstart    = (int*)alloc((BKMAX + 1) * 4);
    int*   gcur      = (int*)alloc(BKMAX * 4);
    int2*  csr       = (int2*)alloc((size_t)E * 8);
    unsigned* A0 = (unsigned*)alloc((size_t)Nf * 2);
    unsigned* L1 = (unsigned*)alloc((size_t)Nf * 2);
    unsigned* L2 = (unsigned*)alloc((size_t)Nf * 2);
    unsigned* L3 = (unsigned*)alloc((size_t)Nf * 2);
    int* mid = (int*)L3;   // alias: mid (E*4B) consumed before L3 is written (gather #3)

    const int B256 = 256;
    auto blocks = [](long long n, int b) { return (int)((n + b - 1) / b); };

    // 1. bucket histogram + bucket scan
    hipMemsetAsync(bcnt, 0, BKMAX * 4, stream);
    bhist_kernel<<<1024, B256, 0, stream>>>(dst, bcnt, E, nbk);
    bscan_kernel<<<1, 512, 0, stream>>>(bcnt, bstart, gcur, nbk, E);

    // 2. place: tile-partition into buckets (4B payload), then per-bucket
    //    degree count + scan (B1) and weighted scatter (B2)
    placeA_kernel<<<blocks(E, TILE), B256, 0, stream>>>(src, dst, gcur, mid, E, nbk);
    placeB1_kernel<<<nbk, 512, 0, stream>>>(bstart, mid, row_start, dis, N, nbk, E);
    placeB2_kernel<<<nbk, 512, 0, stream>>>(bstart, mid, row_start, dis, csr, N);

    // 3. init bf16 A0
    init_kernel<<<blocks(Nf / 2, B256), B256, 0, stream>>>(users, items, A0, nu * D, Nf / 2);

    // 4. propagation: L1..L3 bf16; layer 4 fused with final combine -> f32 d_out
    const int ggrid = blocks(N, B256 / 64);
    gather_kernel<0><<<ggrid, B256, 0, stream>>>(row_start, csr, (const uint2*)A0, (uint2*)L1,
                                                 nullptr, nullptr, nullptr, nullptr, nullptr, N, nu);
    gather_kernel<0><<<ggrid, B256, 0, stream>>>(row_start, csr, (const uint2*)L1, (uint2*)L2,
                                                 nullptr, nullptr, nullptr, nullptr, nullptr, N, nu);
    gather_kernel<0><<<ggrid, B256, 0, stream>>>(row_start, csr, (const uint2*)L2, (uint2*)L3,
                                                 nullptr, nullptr, nullptr, nullptr, nullptr, N, nu);
    gather_kernel<1><<<ggrid, B256, 0, stream>>>(row_start, csr, (const uint2*)L3, nullptr,
                                                 users, items, (const uint2*)L1, (const uint2*)L2,
                                                 (float*)d_out, N, nu);
}